// Round 1
// baseline (918.339 us; speedup 1.0000x reference)
//
#include <hip/hip_runtime.h>
#include <math.h>

// Problem constants (reference: B=50000, W=100, L=10, H=10)
constexpr int W_ = 100;
constexpr int L_ = 10;
constexpr int H_ = 10;
constexpr float NEGV = -99999999.0f;

// One wave (64 lanes) per item b.  Lane owns workers w0=lane, w1=lane+64 (if <100).
// LDS holds temp_abi transposed as [l][m][w]  (10*10*100 floats = 40KB),
// computed per-block from worker_abi (tiny, L2/L3-cached).
__global__ __launch_bounds__(256, 4) void crowd_main_kernel(
    const float* __restrict__ hidden,   // [B,H]
    const float* __restrict__ cmask,    // [B,W,L]
    const float* __restrict__ wemb,     // [W,H]
    const float* __restrict__ wabi,     // [W,L,L]
    float* __restrict__ f_score,        // [B,L]
    float* __restrict__ ob,             // [B,L,W]
    float* __restrict__ obs,            // [B,L,W]
    float* __restrict__ att_out,        // [B,W]
    int B, int totalWaves)
{
    __shared__ float tabi[L_ * L_ * W_];   // [l][m][w]

    // Build temp_abi^T in LDS: softmax over last axis of worker_abi, scattered to [l][m][w].
    for (int idx = threadIdx.x; idx < W_ * L_; idx += blockDim.x) {
        int w = idx / L_;
        int l = idx - w * L_;
        const float* row = wabi + (w * L_ + l) * L_;
        float v[L_];
        float mx = -INFINITY;
#pragma unroll
        for (int m = 0; m < L_; ++m) { v[m] = row[m]; mx = fmaxf(mx, v[m]); }
        float s = 0.f;
#pragma unroll
        for (int m = 0; m < L_; ++m) { v[m] = __expf(v[m] - mx); s += v[m]; }
        float inv = 1.0f / s;
#pragma unroll
        for (int m = 0; m < L_; ++m) tabi[(l * L_ + m) * W_ + w] = v[m] * inv;
    }
    __syncthreads();

    const int lane = threadIdx.x & 63;
    const int wave = blockIdx.x * (blockDim.x >> 6) + (threadIdx.x >> 6);
    const int w0 = lane;             // always < 100
    const int w1 = lane + 64;
    const bool has1 = (w1 < W_);
    const int w1m = has1 ? w1 : 0;   // clamped for safe LDS indexing

    // Worker-emb rows for this lane's workers, reused across all items.
    float we0[H_], we1[H_];
#pragma unroll
    for (int h = 0; h < H_; ++h) we0[h] = wemb[w0 * H_ + h];
#pragma unroll
    for (int h = 0; h < H_; ++h) we1[h] = has1 ? wemb[w1 * H_ + h] : 0.f;

    for (int b = wave; b < B; b += totalWaves) {
        // hidden_sen[b] (broadcast load, L1)
        const float* hp = hidden + (size_t)b * H_;
        float hd[H_];
#pragma unroll
        for (int h = 0; h < H_; ++h) hd[h] = hp[h];

        // crowd_mask rows for the lane's workers (float2-vectorized, 8B aligned)
        const float* cb = cmask + (size_t)b * (W_ * L_);
        float cm0[L_], cm1[L_];
        {
            const float2* p0 = reinterpret_cast<const float2*>(cb + w0 * L_);
#pragma unroll
            for (int j = 0; j < L_ / 2; ++j) {
                float2 t = p0[j]; cm0[2 * j] = t.x; cm0[2 * j + 1] = t.y;
            }
        }
        if (has1) {
            const float2* p1 = reinterpret_cast<const float2*>(cb + w1 * L_);
#pragma unroll
            for (int j = 0; j < L_ / 2; ++j) {
                float2 t = p1[j]; cm1[2 * j] = t.x; cm1[2 * j + 1] = t.y;
            }
        } else {
#pragma unroll
            for (int j = 0; j < L_; ++j) cm1[j] = 0.f;
        }

        // att logits:  (hidden . wemb[w]) * sum_l cmask[w][l];  exact-0 -> NEG
        float cs0 = 0.f, cs1 = 0.f;
#pragma unroll
        for (int j = 0; j < L_; ++j) { cs0 += cm0[j]; cs1 += cm1[j]; }
        float d0 = 0.f, d1 = 0.f;
#pragma unroll
        for (int h = 0; h < H_; ++h) { d0 += hd[h] * we0[h]; d1 += hd[h] * we1[h]; }

        float a0 = d0 * cs0;
        float a1 = d1 * cs1;
        if (a0 == 0.f) a0 = NEGV;
        if (a1 == 0.f) a1 = NEGV;
        if (!has1) a1 = -INFINITY;   // non-existent worker: contributes nothing

        // softmax over the 100 workers (wave butterfly reduce)
        float mx = fmaxf(a0, a1);
#pragma unroll
        for (int off = 32; off >= 1; off >>= 1) mx = fmaxf(mx, __shfl_xor(mx, off));

        float e0 = __expf(a0 - mx);
        float e1 = has1 ? __expf(a1 - mx) : 0.f;
        float s = e0 + e1;
#pragma unroll
        for (int off = 32; off >= 1; off >>= 1) s += __shfl_xor(s, off);
        float inv = 1.0f / s;
        float att0 = e0 * inv;
        float att1 = e1 * inv;

        att_out[(size_t)b * W_ + w0] = att0;
        if (has1) att_out[(size_t)b * W_ + w1] = att1;

        // f_score[l] = sum_w att[w] * cmask[w][l]   (butterfly reduce per l)
        float fs[L_];
#pragma unroll
        for (int l = 0; l < L_; ++l) {
            float p = att0 * cm0[l] + att1 * cm1[l];
#pragma unroll
            for (int off = 32; off >= 1; off >>= 1) p += __shfl_xor(p, off);
            fs[l] = p;
        }
#pragma unroll
        for (int l = 0; l < L_; ++l)
            if (lane == l) f_score[(size_t)b * L_ + l] = fs[l];

        // ob[m] = sum_l fs[l] * tabi[l][m][w]   (stride-1 across lanes -> no bank conflicts)
        float ob0[L_], ob1[L_];
#pragma unroll
        for (int m = 0; m < L_; ++m) {
            float acc0 = 0.f, acc1 = 0.f;
#pragma unroll
            for (int l = 0; l < L_; ++l) {
                acc0 += fs[l] * tabi[(l * L_ + m) * W_ + w0];
                acc1 += fs[l] * tabi[(l * L_ + m) * W_ + w1m];
            }
            ob0[m] = acc0; ob1[m] = acc1;
        }

        float* obp  = ob  + (size_t)b * (L_ * W_);
        float* obsp = obs + (size_t)b * (L_ * W_);
#pragma unroll
        for (int m = 0; m < L_; ++m) {
            obp[m * W_ + w0] = ob0[m];
            if (has1) obp[m * W_ + w1] = ob1[m];
        }

        // softmax over m (in-register, per worker)
        float mx0 = ob0[0], mx1 = ob1[0];
#pragma unroll
        for (int m = 1; m < L_; ++m) { mx0 = fmaxf(mx0, ob0[m]); mx1 = fmaxf(mx1, ob1[m]); }
        float s0 = 0.f, s1 = 0.f;
#pragma unroll
        for (int m = 0; m < L_; ++m) {
            ob0[m] = __expf(ob0[m] - mx0); s0 += ob0[m];
            ob1[m] = __expf(ob1[m] - mx1); s1 += ob1[m];
        }
        float i0 = 1.0f / s0, i1 = 1.0f / s1;
#pragma unroll
        for (int m = 0; m < L_; ++m) {
            obsp[m * W_ + w0] = ob0[m] * i0;
            if (has1) obsp[m * W_ + w1] = ob1[m] * i1;
        }
    }
}

extern "C" void kernel_launch(void* const* d_in, const int* in_sizes, int n_in,
                              void* d_out, int out_size, void* d_ws, size_t ws_size,
                              hipStream_t stream) {
    const float* hidden = (const float*)d_in[0];   // [B,H]
    const float* cmask  = (const float*)d_in[1];   // [B,W,L]
    const float* wemb   = (const float*)d_in[2];   // [W,H]
    const float* wabi   = (const float*)d_in[3];   // [W,L,L]

    const int B = in_sizes[0] / H_;

    // Outputs concatenated flat in return order:
    float* f_score = (float*)d_out;                         // B*L
    float* ob      = f_score + (size_t)B * L_;              // B*L*W
    float* obs     = ob + (size_t)B * L_ * W_;              // B*L*W
    float* att     = obs + (size_t)B * L_ * W_;             // B*W

    const int blocks = 2048;                  // 8192 waves, ~6 items each
    const int totalWaves = blocks * 4;
    crowd_main_kernel<<<blocks, 256, 0, stream>>>(
        hidden, cmask, wemb, wabi, f_score, ob, obs, att, B, totalWaves);
}